// Round 4
// baseline (1454.106 us; speedup 1.0000x reference)
//
#include <hip/hip_runtime.h>
#include <hip/hip_bf16.h>

// Problem constants (from reference)
#define IN_PER_SIDE   40960
#define IN_TOTAL      81920     // 2 * 40960
#define L1            512
#define L2            32
#define L3_           32
#define BATCH         4096
#define MAXIDX        128       // per-row index-list capacity (~60 used)

// clang-native 4-float vector (HIP float4 is a class; builtin rejects it)
typedef float v4f __attribute__((ext_vector_type(4)));

// ws layout: [WT: 81920*512 f32][cnt: 4096 i32][idx: 4096*128 i32]
#define WT_BYTES   ((size_t)IN_TOTAL * L1 * sizeof(float))   // 167,772,160
#define CNT_BYTES  ((size_t)BATCH * sizeof(int))
#define IDX_BYTES  ((size_t)BATCH * MAXIDX * sizeof(int))

// ---------------------------------------------------------------------------
// Kernel A: merged streaming kernel.
//   blockIdx % 9 < 5  -> transpose tile (10240 blocks: 64x64, float4 both
//                        sides, padded LDS, nontemporal read)
//   blockIdx % 9 >= 5 -> feature scan (8192 blocks: 2 per batch row, one per
//                        perspective; compact nonzero indices via global
//                        atomics into per-row lists)
// Interleaving keeps both HBM streams live on every CU simultaneously —
// both halves are pure-BW work, so this removes the inter-kernel tail.
// ---------------------------------------------------------------------------
__global__ __launch_bounds__(256) void stream_prep(
    const float* __restrict__ W, float* __restrict__ WT,
    const float* __restrict__ wf, const float* __restrict__ bfeat,
    int* __restrict__ cnt, int* __restrict__ idxs)
{
    __shared__ float tile[64][65];
    const int cls = blockIdx.x % 9;

    if (cls < 5) {
        // ---- transpose tile ----
        const int tindex = (blockIdx.x / 9) * 5 + cls;    // 0..10239
        const int jt = (tindex % 1280) * 64;              // input-feature base
        const int ot = (tindex / 1280) * 64;              // neuron base
        const int tx = threadIdx.x & 15;
        const int ty = threadIdx.x >> 4;

#pragma unroll
        for (int k = 0; k < 4; ++k) {
            const int o = ty + 16 * k;
            const v4f* p = (const v4f*)&W[(size_t)(ot + o) * IN_TOTAL + jt + 4 * tx];
            v4f v = __builtin_nontemporal_load(p);
            tile[4 * tx + 0][o] = v.x;
            tile[4 * tx + 1][o] = v.y;
            tile[4 * tx + 2][o] = v.z;
            tile[4 * tx + 3][o] = v.w;
        }
        __syncthreads();
#pragma unroll
        for (int k = 0; k < 4; ++k) {
            const int j = ty + 16 * k;
            v4f v;
            v.x = tile[j][4 * tx + 0];
            v.y = tile[j][4 * tx + 1];
            v.z = tile[j][4 * tx + 2];
            v.w = tile[j][4 * tx + 3];
            *(v4f*)&WT[(size_t)(jt + j) * L1 + ot + 4 * tx] = v;
        }
    } else {
        // ---- feature scan: one perspective row ----
        const int sindex = (blockIdx.x / 9) * 4 + (cls - 5);  // 0..8191
        const int row  = sindex >> 1;
        const int side = sindex & 1;
        const float* src = side ? bfeat : wf;
        const int    bias = side ? IN_PER_SIDE : 0;
        const v4f* p = (const v4f*)(src + (size_t)row * IN_PER_SIDE);
        int* ic = cnt + row;
        int* il = idxs + (size_t)row * MAXIDX;

        const int nvec = IN_PER_SIDE / 4;   // 10240
        for (int i = threadIdx.x; i < nvec; i += 256) {
            v4f v = __builtin_nontemporal_load(p + i);
            if (v.x != 0.0f) il[atomicAdd(ic, 1)] = bias + 4 * i + 0;
            if (v.y != 0.0f) il[atomicAdd(ic, 1)] = bias + 4 * i + 1;
            if (v.z != 0.0f) il[atomicAdd(ic, 1)] = bias + 4 * i + 2;
            if (v.w != 0.0f) il[atomicAdd(ic, 1)] = bias + 4 * i + 3;
        }
    }
}

// ---------------------------------------------------------------------------
// Kernel B: gather + MLP. One block per batch row, 512 threads.
//   Phase 2: thread t = neuron t; accumulate active WT columns (coalesced
//            2 KB reads, WT is L3-resident; unroll 8 for MLP)
//   Phase 3-5: tiny dense layers, shuffle reductions, no atomics
// ---------------------------------------------------------------------------
__global__ __launch_bounds__(512) void gather_mlp(
    const float* __restrict__ WT,
    const int* __restrict__ cnt, const int* __restrict__ idxs,
    const float* __restrict__ b_in,
    const float* __restrict__ W1, const float* __restrict__ b1,
    const float* __restrict__ W2, const float* __restrict__ b2,
    const float* __restrict__ W3, const float* __restrict__ b3,
    float* __restrict__ out)
{
    const int b = blockIdx.x;
    const int t = threadIdx.x;

    __shared__ int   sidx[MAXIDX];
    __shared__ float l1s[L1];
    __shared__ float l2acc[L2];
    __shared__ float l2s[L2];
    __shared__ float l3s[L3_];

    const int n = cnt[b];
    if (t < n) sidx[t] = idxs[(size_t)b * MAXIDX + t];   // n <= 128 <= 512
    const float bias_t = b_in[t];
    __syncthreads();

    float a0 = 0.0f, a1 = 0.0f, a2 = 0.0f, a3 = 0.0f;
    int i = 0;
    for (; i + 8 <= n; i += 8) {
        const float v0 = WT[(size_t)sidx[i + 0] * L1 + t];
        const float v1 = WT[(size_t)sidx[i + 1] * L1 + t];
        const float v2 = WT[(size_t)sidx[i + 2] * L1 + t];
        const float v3 = WT[(size_t)sidx[i + 3] * L1 + t];
        const float v4 = WT[(size_t)sidx[i + 4] * L1 + t];
        const float v5 = WT[(size_t)sidx[i + 5] * L1 + t];
        const float v6 = WT[(size_t)sidx[i + 6] * L1 + t];
        const float v7 = WT[(size_t)sidx[i + 7] * L1 + t];
        a0 += v0; a1 += v1; a2 += v2; a3 += v3;
        a0 += v4; a1 += v5; a2 += v6; a3 += v7;
    }
    for (; i < n; ++i) a0 += WT[(size_t)sidx[i] * L1 + t];

    float acc = bias_t + ((a0 + a1) + (a2 + a3));
    l1s[t] = fminf(fmaxf(acc, 0.0f), 1.0f);
    __syncthreads();

    // ---- l2 = clip(l1 @ W1.T + b1): output k owned by 16 lanes (same wave)
    {
        const int k = t >> 4;
        const int g = t & 15;
        const float* w = W1 + (size_t)k * L1;
        float p = 0.0f;
        for (int o = g; o < L1; o += 16) p += w[o] * l1s[o];
#pragma unroll
        for (int off = 8; off > 0; off >>= 1) p += __shfl_down(p, off, 16);
        if (g == 0) l2acc[k] = p;
    }
    __syncthreads();
    if (t < L2) l2s[t] = fminf(fmaxf(l2acc[t] + b1[t], 0.0f), 1.0f);
    __syncthreads();

    // ---- l3 = clip(l2 @ W2.T + b2), 32x32
    if (t < L3_) {
        const float* w = W2 + (size_t)t * L2;
        float p = b2[t];
#pragma unroll
        for (int q = 0; q < L2; ++q) p += w[q] * l2s[q];
        l3s[t] = fminf(fmaxf(p, 0.0f), 1.0f);
    }
    __syncthreads();

    // ---- out = l3 @ W3.T + b3
    if (t == 0) {
        float p = b3[0];
#pragma unroll
        for (int q = 0; q < L3_; ++q) p += W3[q] * l3s[q];
        out[b] = p;
    }
}

// ---------------------------------------------------------------------------
// Fallback (ws too small for WT + lists): round-1-style fused kernel reading
// W_in columns directly. Correct but slow; not expected to run (ws ~2.5 GiB).
// ---------------------------------------------------------------------------
__global__ __launch_bounds__(512) void nnue_fallback(
    const float* __restrict__ wf, const float* __restrict__ bfeat,
    const float* __restrict__ W_in, const float* __restrict__ b_in,
    const float* __restrict__ W1, const float* __restrict__ b1,
    const float* __restrict__ W2, const float* __restrict__ b2,
    const float* __restrict__ W3, const float* __restrict__ b3,
    float* __restrict__ out)
{
    const int b = blockIdx.x;
    const int t = threadIdx.x;
    __shared__ int   idxs[MAXIDX];
    __shared__ int   scnt;
    __shared__ float l1s[L1];
    __shared__ float l2acc[L2];
    __shared__ float l2s[L2];
    __shared__ float l3s[L3_];

    if (t == 0) scnt = 0;
    __syncthreads();
    const v4f* wrow = (const v4f*)(wf    + (size_t)b * IN_PER_SIDE);
    const v4f* brow = (const v4f*)(bfeat + (size_t)b * IN_PER_SIDE);
    for (int i = t; i < IN_PER_SIDE / 4; i += 512) {
        v4f v = wrow[i];
        if (v.x != 0.0f) idxs[atomicAdd(&scnt, 1)] = 4 * i + 0;
        if (v.y != 0.0f) idxs[atomicAdd(&scnt, 1)] = 4 * i + 1;
        if (v.z != 0.0f) idxs[atomicAdd(&scnt, 1)] = 4 * i + 2;
        if (v.w != 0.0f) idxs[atomicAdd(&scnt, 1)] = 4 * i + 3;
        v4f u = brow[i];
        if (u.x != 0.0f) idxs[atomicAdd(&scnt, 1)] = IN_PER_SIDE + 4 * i + 0;
        if (u.y != 0.0f) idxs[atomicAdd(&scnt, 1)] = IN_PER_SIDE + 4 * i + 1;
        if (u.z != 0.0f) idxs[atomicAdd(&scnt, 1)] = IN_PER_SIDE + 4 * i + 2;
        if (u.w != 0.0f) idxs[atomicAdd(&scnt, 1)] = IN_PER_SIDE + 4 * i + 3;
    }
    __syncthreads();
    const int n = scnt;
    float a0 = 0.0f;
    const float* wr = W_in + (size_t)t;  // column t, stride IN_TOTAL? no:
    // W_in is [512, 81920] row-major; neuron t row base:
    const float* row = W_in + (size_t)t * IN_TOTAL;
    for (int i = 0; i < n; ++i) a0 += row[idxs[i]];
    l1s[t] = fminf(fmaxf(b_in[t] + a0, 0.0f), 1.0f);
    __syncthreads();
    {
        const int k = t >> 4, g = t & 15;
        const float* w = W1 + (size_t)k * L1;
        float p = 0.0f;
        for (int o = g; o < L1; o += 16) p += w[o] * l1s[o];
#pragma unroll
        for (int off = 8; off > 0; off >>= 1) p += __shfl_down(p, off, 16);
        if (g == 0) l2acc[k] = p;
    }
    __syncthreads();
    if (t < L2) l2s[t] = fminf(fmaxf(l2acc[t] + b1[t], 0.0f), 1.0f);
    __syncthreads();
    if (t < L3_) {
        const float* w = W2 + (size_t)t * L2;
        float p = b2[t];
#pragma unroll
        for (int q = 0; q < L2; ++q) p += w[q] * l2s[q];
        l3s[t] = fminf(fmaxf(p, 0.0f), 1.0f);
    }
    __syncthreads();
    if (t == 0) {
        float p = b3[0];
#pragma unroll
        for (int q = 0; q < L3_; ++q) p += W3[q] * l3s[q];
        out[b] = p;
    }
}

extern "C" void kernel_launch(void* const* d_in, const int* in_sizes, int n_in,
                              void* d_out, int out_size, void* d_ws, size_t ws_size,
                              hipStream_t stream) {
    const float* wf   = (const float*)d_in[0];
    const float* bfeat= (const float*)d_in[1];
    const float* W_in = (const float*)d_in[2];
    const float* b_in = (const float*)d_in[3];
    const float* W1   = (const float*)d_in[4];
    const float* b1   = (const float*)d_in[5];
    const float* W2   = (const float*)d_in[6];
    const float* b2   = (const float*)d_in[7];
    const float* W3   = (const float*)d_in[8];
    const float* b3   = (const float*)d_in[9];
    float* out = (float*)d_out;

    const size_t need = WT_BYTES + CNT_BYTES + IDX_BYTES;
    if (ws_size >= need) {
        float* WT  = (float*)d_ws;
        int*   cnt = (int*)((char*)d_ws + WT_BYTES);
        int*   idx = (int*)((char*)d_ws + WT_BYTES + CNT_BYTES);

        // ws is re-poisoned to 0xAA before every call: zero the counters.
        hipMemsetAsync(cnt, 0, CNT_BYTES, stream);

        stream_prep<<<18432, 256, 0, stream>>>(W_in, WT, wf, bfeat, cnt, idx);
        gather_mlp<<<BATCH, 512, 0, stream>>>(WT, cnt, idx, b_in,
                                              W1, b1, W2, b2, W3, b3, out);
    } else {
        nnue_fallback<<<BATCH, 512, 0, stream>>>(
            wf, bfeat, W_in, b_in, W1, b1, W2, b2, W3, b3, out);
    }
}

// Round 5
// 1362.023 us; speedup vs baseline: 1.0676x; 1.0676x over previous
//
#include <hip/hip_runtime.h>
#include <hip/hip_bf16.h>

// Problem constants (from reference)
#define IN_PER_SIDE   40960
#define IN_TOTAL      81920     // 2 * 40960
#define L1            512
#define L2            32
#define L3_           32
#define BATCH         4096
#define MAXIDX        128       // per-row index capacity (~60 used)

// clang-native 4-float vector (HIP float4 is a class; builtins reject it)
typedef float v4f __attribute__((ext_vector_type(4)));

#define WT_BYTES ((size_t)IN_TOTAL * L1 * sizeof(float))   // 167.8 MB

// ---------------------------------------------------------------------------
// Kernel 1: LDS-tiled transpose W_in [512, 81920] -> W_T [81920, 512].
// 64x64 tiles, float4 on both global sides; pad 65 keeps LDS <=2-way (free).
// Nontemporal READ (W_in used once; keep L3 for WT). Regular WRITE (we WANT
// WT resident in L2/L3 for the gather).
// ---------------------------------------------------------------------------
__global__ __launch_bounds__(256) void transpose_win(
    const float* __restrict__ W, float* __restrict__ WT)
{
    __shared__ float tile[64][65];
    const int jt = blockIdx.x * 64;           // input-feature tile base
    const int ot = blockIdx.y * 64;           // output-neuron tile base
    const int tx = threadIdx.x & 15;          // float4 column
    const int ty = threadIdx.x >> 4;          // row

#pragma unroll
    for (int k = 0; k < 4; ++k) {
        const int o = ty + 16 * k;
        const v4f* p = (const v4f*)&W[(size_t)(ot + o) * IN_TOTAL + jt + 4 * tx];
        v4f v = __builtin_nontemporal_load(p);
        tile[4 * tx + 0][o] = v.x;
        tile[4 * tx + 1][o] = v.y;
        tile[4 * tx + 2][o] = v.z;
        tile[4 * tx + 3][o] = v.w;
    }
    __syncthreads();
#pragma unroll
    for (int k = 0; k < 4; ++k) {
        const int j = ty + 16 * k;
        v4f v;
        v.x = tile[j][4 * tx + 0];
        v.y = tile[j][4 * tx + 1];
        v.z = tile[j][4 * tx + 2];
        v.w = tile[j][4 * tx + 3];
        *(v4f*)&WT[(size_t)(jt + j) * L1 + ot + 4 * tx] = v;
    }
}

// ---------------------------------------------------------------------------
// Kernel 2: fused NNUE forward, one block per batch row, 512 threads.
//   Phase 1 (scan):   nontemporal float4 stream; values are {0,1} so a sum
//                     test rejects all-zero vectors with one compare.
//   Phase 2 (gather): 4 groups x 128 lanes; one feature = 128 lanes x float4
//                     = one coalesced 2 KB read of WT (L3-resident). Unroll 2.
//                     Cross-group reduce via conflict-free LDS pass.
//   Phase 3-5: tiny dense layers, shuffle reductions, no atomics.
// Block-level overlap: scan is HBM-BW-bound, gather is L3-latency-bound;
// blocks in different phases overlap naturally across the 4096-block grid.
// ---------------------------------------------------------------------------
__global__ __launch_bounds__(512) void nnue_fused(
    const float* __restrict__ wf, const float* __restrict__ bfeat,
    const float* __restrict__ WT, const float* __restrict__ W_in, int use_wt,
    const float* __restrict__ b_in,
    const float* __restrict__ W1, const float* __restrict__ b1,
    const float* __restrict__ W2, const float* __restrict__ b2,
    const float* __restrict__ W3, const float* __restrict__ b3,
    float* __restrict__ out)
{
    const int b = blockIdx.x;
    const int t = threadIdx.x;

    __shared__ int   sidx[MAXIDX];
    __shared__ int   scnt;
    __shared__ v4f   accs[4][128];
    __shared__ float l1s[L1];
    __shared__ float l2acc[L2];
    __shared__ float l2s[L2];
    __shared__ float l3s[L3_];

    if (t == 0) scnt = 0;
    __syncthreads();

    // ---- Phase 1: scan both perspective rows (values are exactly 0.0/1.0)
    const v4f* wrow = (const v4f*)(wf    + (size_t)b * IN_PER_SIDE);
    const v4f* brow = (const v4f*)(bfeat + (size_t)b * IN_PER_SIDE);
    const int nvec = IN_PER_SIDE / 4;  // 10240 float4 per side

    for (int i = t; i < nvec; i += 512) {
        v4f v = __builtin_nontemporal_load(wrow + i);
        if (v.x + v.y + v.z + v.w != 0.0f) {
            if (v.x != 0.0f) sidx[atomicAdd(&scnt, 1)] = 4 * i + 0;
            if (v.y != 0.0f) sidx[atomicAdd(&scnt, 1)] = 4 * i + 1;
            if (v.z != 0.0f) sidx[atomicAdd(&scnt, 1)] = 4 * i + 2;
            if (v.w != 0.0f) sidx[atomicAdd(&scnt, 1)] = 4 * i + 3;
        }
        v4f u = __builtin_nontemporal_load(brow + i);
        if (u.x + u.y + u.z + u.w != 0.0f) {
            if (u.x != 0.0f) sidx[atomicAdd(&scnt, 1)] = IN_PER_SIDE + 4 * i + 0;
            if (u.y != 0.0f) sidx[atomicAdd(&scnt, 1)] = IN_PER_SIDE + 4 * i + 1;
            if (u.z != 0.0f) sidx[atomicAdd(&scnt, 1)] = IN_PER_SIDE + 4 * i + 2;
            if (u.w != 0.0f) sidx[atomicAdd(&scnt, 1)] = IN_PER_SIDE + 4 * i + 3;
        }
    }
    __syncthreads();

    // ---- Phase 2: gather active WT columns.
    const int n = scnt;
    const int g = t >> 7;          // group 0..3
    const int l = t & 127;         // lane within group
    v4f acc0 = {0.0f, 0.0f, 0.0f, 0.0f};
    v4f acc1 = {0.0f, 0.0f, 0.0f, 0.0f};

    if (use_wt) {
        const v4f* WT4 = (const v4f*)WT;   // feature f -> WT4[f*128 + l]
        int k = g;
        for (; k + 8 <= n; k += 8) {
            v4f w0 = WT4[(size_t)sidx[k]     * 128 + l];
            v4f w1 = WT4[(size_t)sidx[k + 4] * 128 + l];
            acc0 += w0;
            acc1 += w1;
        }
        for (; k < n; k += 4) acc0 += WT4[(size_t)sidx[k] * 128 + l];
        accs[g][l] = acc0 + acc1;
    } else {
        // fallback: strided reads straight from W_in (slow, correct):
        // group handles neurons via scalar path; reuse same reduce layout.
        v4f a = {0.0f, 0.0f, 0.0f, 0.0f};
        if (g == 0) {
            // only group 0 does work in fallback (keeps reduce simple):
            // lane l covers neurons 4l..4l+3
            for (int k = 0; k < n; ++k) {
                const int j = sidx[k];
                a.x += W_in[(size_t)(4 * l + 0) * IN_TOTAL + j];
                a.y += W_in[(size_t)(4 * l + 1) * IN_TOTAL + j];
                a.z += W_in[(size_t)(4 * l + 2) * IN_TOTAL + j];
                a.w += W_in[(size_t)(4 * l + 3) * IN_TOTAL + j];
            }
        }
        accs[g][l] = a;
    }
    __syncthreads();

    // ---- reduce groups + bias + clipped ReLU; thread t = neuron t.
    // accs[g'][t>>2][t&3]: consecutive t -> consecutive LDS words (no conflict)
    {
        const int ll = t >> 2, c = t & 3;
        float s = accs[0][ll][c] + accs[1][ll][c] + accs[2][ll][c] + accs[3][ll][c];
        l1s[t] = fminf(fmaxf(s + b_in[t], 0.0f), 1.0f);
    }
    __syncthreads();

    // ---- Phase 3: l2 = clip(l1 @ W1.T + b1): output k owned by 16 lanes
    {
        const int k = t >> 4;
        const int gg = t & 15;
        const float* w = W1 + (size_t)k * L1;
        float p = 0.0f;
        for (int o = gg; o < L1; o += 16) p += w[o] * l1s[o];
#pragma unroll
        for (int off = 8; off > 0; off >>= 1) p += __shfl_down(p, off, 16);
        if (gg == 0) l2acc[k] = p;
    }
    __syncthreads();
    if (t < L2) l2s[t] = fminf(fmaxf(l2acc[t] + b1[t], 0.0f), 1.0f);
    __syncthreads();

    // ---- Phase 4: l3 = clip(l2 @ W2.T + b2), 32x32
    if (t < L3_) {
        const float* w = W2 + (size_t)t * L2;
        float p = b2[t];
#pragma unroll
        for (int q = 0; q < L2; ++q) p += w[q] * l2s[q];
        l3s[t] = fminf(fmaxf(p, 0.0f), 1.0f);
    }
    __syncthreads();

    // ---- Phase 5: out = l3 @ W3.T + b3
    if (t == 0) {
        float p = b3[0];
#pragma unroll
        for (int q = 0; q < L3_; ++q) p += W3[q] * l3s[q];
        out[b] = p;
    }
}

extern "C" void kernel_launch(void* const* d_in, const int* in_sizes, int n_in,
                              void* d_out, int out_size, void* d_ws, size_t ws_size,
                              hipStream_t stream) {
    const float* wf   = (const float*)d_in[0];
    const float* bfeat= (const float*)d_in[1];
    const float* W_in = (const float*)d_in[2];
    const float* b_in = (const float*)d_in[3];
    const float* W1   = (const float*)d_in[4];
    const float* b1   = (const float*)d_in[5];
    const float* W2   = (const float*)d_in[6];
    const float* b2   = (const float*)d_in[7];
    const float* W3   = (const float*)d_in[8];
    const float* b3   = (const float*)d_in[9];
    float* out = (float*)d_out;

    const int use_wt = (ws_size >= WT_BYTES) ? 1 : 0;
    float* WT = (float*)d_ws;

    if (use_wt) {
        dim3 grid(IN_TOTAL / 64, L1 / 64);   // (1280, 8)
        transpose_win<<<grid, 256, 0, stream>>>(W_in, WT);
    }

    nnue_fused<<<BATCH, 512, 0, stream>>>(
        wf, bfeat, WT, W_in, use_wt, b_in, W1, b1, W2, b2, W3, b3, out);
}

// Round 6
// 1302.924 us; speedup vs baseline: 1.1160x; 1.0454x over previous
//
#include <hip/hip_runtime.h>
#include <hip/hip_bf16.h>

// Problem constants (from reference)
#define IN_PER_SIDE   40960
#define IN_TOTAL      81920     // 2 * 40960
#define L1            512
#define L2            32
#define L3_           32
#define BATCH         4096
#define MAXIDX        128       // per-row index capacity (~60 used)

// clang-native vectors (HIP float4 is a class; builtins reject it)
typedef float    v4f __attribute__((ext_vector_type(4)));
typedef float    v8f __attribute__((ext_vector_type(8)));
typedef _Float16 v4h __attribute__((ext_vector_type(4)));
typedef _Float16 v8h __attribute__((ext_vector_type(8)));

// WT stored as fp16: 81920 * 512 * 2 B = 83.9 MB (halves write + gather traffic;
// |W_in| <= 0.0035 so fp16 abs err ~1.7e-6/entry -> output err ~1e-5, thr 4.6e-4)
#define WT_BYTES ((size_t)IN_TOTAL * L1 * sizeof(_Float16))

// ---------------------------------------------------------------------------
// Kernel 1: LDS-tiled transpose W_in [512, 81920] f32 -> WTh [81920, 512] f16.
// 64x64 tiles, float4 global reads (nontemporal: W_in used once, keep L3 for
// WTh), 8 B fp16 writes (16 lanes x 8 B = 128 B contiguous per row segment).
// ---------------------------------------------------------------------------
__global__ __launch_bounds__(256) void transpose_win(
    const float* __restrict__ W, _Float16* __restrict__ WTh)
{
    __shared__ float tile[64][65];
    const int jt = blockIdx.x * 64;           // input-feature tile base
    const int ot = blockIdx.y * 64;           // output-neuron tile base
    const int tx = threadIdx.x & 15;          // float4 column
    const int ty = threadIdx.x >> 4;          // row

#pragma unroll
    for (int k = 0; k < 4; ++k) {
        const int o = ty + 16 * k;
        const v4f* p = (const v4f*)&W[(size_t)(ot + o) * IN_TOTAL + jt + 4 * tx];
        v4f v = __builtin_nontemporal_load(p);
        tile[4 * tx + 0][o] = v.x;
        tile[4 * tx + 1][o] = v.y;
        tile[4 * tx + 2][o] = v.z;
        tile[4 * tx + 3][o] = v.w;
    }
    __syncthreads();
#pragma unroll
    for (int k = 0; k < 4; ++k) {
        const int j = ty + 16 * k;
        v4f v;
        v.x = tile[j][4 * tx + 0];
        v.y = tile[j][4 * tx + 1];
        v.z = tile[j][4 * tx + 2];
        v.w = tile[j][4 * tx + 3];
        v4h h = __builtin_convertvector(v, v4h);
        *(v4h*)&WTh[(size_t)(jt + j) * L1 + ot + 4 * tx] = h;
    }
}

// ---------------------------------------------------------------------------
// Kernel 2: fused NNUE forward, one block per batch row, 512 threads.
//   Phase 1 (scan):   nontemporal float4 stream; {0,1} values -> sum test
//                     rejects all-zero vectors with one compare.
//   Phase 2 (gather): 8 waves x 64 lanes; one feature = 512 fp16 = 1 KB =
//                     ONE wave64 x 16 B coalesced load. Wave w owns features
//                     w, w+8, ... (8 features in flight; unroll 2 -> 16).
//                     fp32 accumulate; cross-wave reduce via pad-9 LDS
//                     (9 odd -> every access <=2-way bank alias = free).
//   Phase 3-5: tiny dense layers, shuffle reductions, no atomics.
// Scan (HBM-BW-bound) and gather (L3-latency-bound) overlap across blocks.
// ---------------------------------------------------------------------------
__global__ __launch_bounds__(512) void nnue_fused(
    const float* __restrict__ wf, const float* __restrict__ bfeat,
    const _Float16* __restrict__ WTh,
    const float* __restrict__ b_in,
    const float* __restrict__ W1, const float* __restrict__ b1,
    const float* __restrict__ W2, const float* __restrict__ b2,
    const float* __restrict__ W3, const float* __restrict__ b3,
    float* __restrict__ out)
{
    const int b = blockIdx.x;
    const int t = threadIdx.x;

    __shared__ int   sidx[MAXIDX];
    __shared__ int   scnt;
    __shared__ float accs[8 * 64 * 9];   // [wave][lane][8 neurons + pad]
    __shared__ float l1s[L1];
    __shared__ float l2acc[L2];
    __shared__ float l2s[L2];
    __shared__ float l3s[L3_];

    if (t == 0) scnt = 0;
    __syncthreads();

    // ---- Phase 1: scan both perspective rows (values are exactly 0.0/1.0)
    const v4f* wrow = (const v4f*)(wf    + (size_t)b * IN_PER_SIDE);
    const v4f* brow = (const v4f*)(bfeat + (size_t)b * IN_PER_SIDE);
    const int nvec = IN_PER_SIDE / 4;  // 10240 float4 per side

    for (int i = t; i < nvec; i += 512) {
        v4f v = __builtin_nontemporal_load(wrow + i);
        if (v.x + v.y + v.z + v.w != 0.0f) {
            if (v.x != 0.0f) sidx[atomicAdd(&scnt, 1)] = 4 * i + 0;
            if (v.y != 0.0f) sidx[atomicAdd(&scnt, 1)] = 4 * i + 1;
            if (v.z != 0.0f) sidx[atomicAdd(&scnt, 1)] = 4 * i + 2;
            if (v.w != 0.0f) sidx[atomicAdd(&scnt, 1)] = 4 * i + 3;
        }
        v4f u = __builtin_nontemporal_load(brow + i);
        if (u.x + u.y + u.z + u.w != 0.0f) {
            if (u.x != 0.0f) sidx[atomicAdd(&scnt, 1)] = IN_PER_SIDE + 4 * i + 0;
            if (u.y != 0.0f) sidx[atomicAdd(&scnt, 1)] = IN_PER_SIDE + 4 * i + 1;
            if (u.z != 0.0f) sidx[atomicAdd(&scnt, 1)] = IN_PER_SIDE + 4 * i + 2;
            if (u.w != 0.0f) sidx[atomicAdd(&scnt, 1)] = IN_PER_SIDE + 4 * i + 3;
        }
    }
    __syncthreads();

    // ---- Phase 2: gather active WTh columns; wave w, lane l.
    const int n = scnt;
    const int w = t >> 6;          // wave 0..7
    const int l = t & 63;          // lane 0..63
    const v8h* WTH8 = (const v8h*)WTh;   // feature f -> WTH8[f*64 + l]

    v8f acc0 = {0,0,0,0,0,0,0,0};
    v8f acc1 = {0,0,0,0,0,0,0,0};
    int k = w;
    for (; k + 16 <= n; k += 16) {
        v8h h0 = WTH8[(size_t)sidx[k]     * 64 + l];
        v8h h1 = WTH8[(size_t)sidx[k + 8] * 64 + l];
        acc0 += __builtin_convertvector(h0, v8f);
        acc1 += __builtin_convertvector(h1, v8f);
    }
    for (; k < n; k += 8)
        acc0 += __builtin_convertvector(WTH8[(size_t)sidx[k] * 64 + l], v8f);
    acc0 += acc1;

    // scalar LDS stores at pad-9 stride: bank = (9*l + i) % 32, 9 odd ->
    // distinct over 32 lanes per i -> conflict-free.
    {
        float* dst = &accs[(w * 64 + l) * 9];
#pragma unroll
        for (int i = 0; i < 8; ++i) dst[i] = acc0[i];
    }
    __syncthreads();

    // ---- reduce waves + bias + clipped ReLU; thread t = neuron t.
    {
        const int ll = t >> 3, c = t & 7;
        float s = 0.0f;
#pragma unroll
        for (int ww = 0; ww < 8; ++ww) s += accs[(ww * 64 + ll) * 9 + c];
        l1s[t] = fminf(fmaxf(s + b_in[t], 0.0f), 1.0f);
    }
    __syncthreads();

    // ---- Phase 3: l2 = clip(l1 @ W1.T + b1): output k owned by 16 lanes
    {
        const int kk = t >> 4;
        const int gg = t & 15;
        const float* wp = W1 + (size_t)kk * L1;
        float p = 0.0f;
        for (int o = gg; o < L1; o += 16) p += wp[o] * l1s[o];
#pragma unroll
        for (int off = 8; off > 0; off >>= 1) p += __shfl_down(p, off, 16);
        if (gg == 0) l2acc[kk] = p;
    }
    __syncthreads();
    if (t < L2) l2s[t] = fminf(fmaxf(l2acc[t] + b1[t], 0.0f), 1.0f);
    __syncthreads();

    // ---- Phase 4: l3 = clip(l2 @ W2.T + b2), 32x32
    if (t < L3_) {
        const float* wp = W2 + (size_t)t * L2;
        float p = b2[t];
#pragma unroll
        for (int q = 0; q < L2; ++q) p += wp[q] * l2s[q];
        l3s[t] = fminf(fmaxf(p, 0.0f), 1.0f);
    }
    __syncthreads();

    // ---- Phase 5: out = l3 @ W3.T + b3
    if (t == 0) {
        float p = b3[0];
#pragma unroll
        for (int q = 0; q < L3_; ++q) p += W3[q] * l3s[q];
        out[b] = p;
    }
}

// ---------------------------------------------------------------------------
// Fallback (ws too small for WTh): fused kernel reading W_in columns
// directly. Correct but slow; not expected to run (ws ~2.5 GiB >> 84 MB).
// ---------------------------------------------------------------------------
__global__ __launch_bounds__(512) void nnue_fallback(
    const float* __restrict__ wf, const float* __restrict__ bfeat,
    const float* __restrict__ W_in, const float* __restrict__ b_in,
    const float* __restrict__ W1, const float* __restrict__ b1,
    const float* __restrict__ W2, const float* __restrict__ b2,
    const float* __restrict__ W3, const float* __restrict__ b3,
    float* __restrict__ out)
{
    const int b = blockIdx.x;
    const int t = threadIdx.x;
    __shared__ int   idxs[MAXIDX];
    __shared__ int   scnt;
    __shared__ float l1s[L1];
    __shared__ float l2acc[L2];
    __shared__ float l2s[L2];
    __shared__ float l3s[L3_];

    if (t == 0) scnt = 0;
    __syncthreads();
    const v4f* wrow = (const v4f*)(wf    + (size_t)b * IN_PER_SIDE);
    const v4f* brow = (const v4f*)(bfeat + (size_t)b * IN_PER_SIDE);
    for (int i = t; i < IN_PER_SIDE / 4; i += 512) {
        v4f v = wrow[i];
        if (v.x != 0.0f) idxs[atomicAdd(&scnt, 1)] = 4 * i + 0;
        if (v.y != 0.0f) idxs[atomicAdd(&scnt, 1)] = 4 * i + 1;
        if (v.z != 0.0f) idxs[atomicAdd(&scnt, 1)] = 4 * i + 2;
        if (v.w != 0.0f) idxs[atomicAdd(&scnt, 1)] = 4 * i + 3;
        v4f u = brow[i];
        if (u.x != 0.0f) idxs[atomicAdd(&scnt, 1)] = IN_PER_SIDE + 4 * i + 0;
        if (u.y != 0.0f) idxs[atomicAdd(&scnt, 1)] = IN_PER_SIDE + 4 * i + 1;
        if (u.z != 0.0f) idxs[atomicAdd(&scnt, 1)] = IN_PER_SIDE + 4 * i + 2;
        if (u.w != 0.0f) idxs[atomicAdd(&scnt, 1)] = IN_PER_SIDE + 4 * i + 3;
    }
    __syncthreads();
    const int n = scnt;
    float a0 = 0.0f;
    const float* row = W_in + (size_t)t * IN_TOTAL;
    for (int i = 0; i < n; ++i) a0 += row[idxs[i]];
    l1s[t] = fminf(fmaxf(b_in[t] + a0, 0.0f), 1.0f);
    __syncthreads();
    {
        const int k = t >> 4, g = t & 15;
        const float* wp = W1 + (size_t)k * L1;
        float p = 0.0f;
        for (int o = g; o < L1; o += 16) p += wp[o] * l1s[o];
#pragma unroll
        for (int off = 8; off > 0; off >>= 1) p += __shfl_down(p, off, 16);
        if (g == 0) l2acc[k] = p;
    }
    __syncthreads();
    if (t < L2) l2s[t] = fminf(fmaxf(l2acc[t] + b1[t], 0.0f), 1.0f);
    __syncthreads();
    if (t < L3_) {
        const float* wp = W2 + (size_t)t * L2;
        float p = b2[t];
#pragma unroll
        for (int q = 0; q < L2; ++q) p += wp[q] * l2s[q];
        l3s[t] = fminf(fmaxf(p, 0.0f), 1.0f);
    }
    __syncthreads();
    if (t == 0) {
        float p = b3[0];
#pragma unroll
        for (int q = 0; q < L3_; ++q) p += W3[q] * l3s[q];
        out[b] = p;
    }
}

extern "C" void kernel_launch(void* const* d_in, const int* in_sizes, int n_in,
                              void* d_out, int out_size, void* d_ws, size_t ws_size,
                              hipStream_t stream) {
    const float* wf   = (const float*)d_in[0];
    const float* bfeat= (const float*)d_in[1];
    const float* W_in = (const float*)d_in[2];
    const float* b_in = (const float*)d_in[3];
    const float* W1   = (const float*)d_in[4];
    const float* b1   = (const float*)d_in[5];
    const float* W2   = (const float*)d_in[6];
    const float* b2   = (const float*)d_in[7];
    const float* W3   = (const float*)d_in[8];
    const float* b3   = (const float*)d_in[9];
    float* out = (float*)d_out;

    if (ws_size >= WT_BYTES) {
        _Float16* WTh = (_Float16*)d_ws;
        dim3 grid(IN_TOTAL / 64, L1 / 64);   // (1280, 8)
        transpose_win<<<grid, 256, 0, stream>>>(W_in, WTh);
        nnue_fused<<<BATCH, 512, 0, stream>>>(
            wf, bfeat, WTh, b_in, W1, b1, W2, b2, W3, b3, out);
    } else {
        nnue_fallback<<<BATCH, 512, 0, stream>>>(
            wf, bfeat, W_in, b_in, W1, b1, W2, b2, W3, b3, out);
    }
}